// Round 5
// baseline (794.196 us; speedup 1.0000x reference)
//
#include <hip/hip_runtime.h>

// Fusedmax: out = sparsemax(prox_TV1D(x, alpha=1)) row-wise. B=4096, N=512, fp32.
// R5 = R4 with the right-scan pop predicate fixed (was sign-inverted; correct
// is POP WHILE -(ahi*x+bhi) >= lam, matching R2/R3 which passed).
// Design: Johnson DP, register-windowed deque:
//  - top-2 knots per side in registers (L0,L1 / R0,R1), write-through pushes
//    (ds_write_b128, knots packed float4). Pop<=1 + push needs NO LDS read;
//    only pop>=2 (rare) rescans from LDS and rebuilds the window.
//  - window invariants: L0=kq[l], L1=kq[l+1], R0=kq[r], R1=kq[r-1];
//    cross-side fixups when the deque is 2 deep; fast path gated on size>=3.
//  - LDS = ys(2KB, y->tm->beta overlay) + knot ring float4[512] (8KB) = 10240B
//    -> 16 blocks/CU -> ALL 4096 rows resident in one generation.
//  - tp spills to d_out (row-local scratch; d_ws untouched — R2's OOB lesson),
//    prefetched float4 readback in the backward pass.

#define TVN 512
#define LAM 1.0f
#define RMASK 511

__device__ __forceinline__ float wave_reduce_sum(float v) {
#pragma unroll
    for (int off = 32; off > 0; off >>= 1) v += __shfl_xor(v, off, 64);
    return v;
}

struct Knot { float x, a, b; };

__global__ __launch_bounds__(64, 4) void fusedmax_kernel(const float* __restrict__ xin,
                                                         float* __restrict__ out) {
    __shared__ __align__(16) float ys[TVN];     // y -> tm overlay -> beta overlay
    __shared__ __align__(16) float4 kq[TVN];    // knot ring: {x, a, b, pad}

    const int t = threadIdx.x;
    const int row = blockIdx.x;
    float* __restrict__ tpr = out + (size_t)row * TVN;   // tp scratch in d_out (row-local)

    const float4* __restrict__ g4 = (const float4*)(xin + (size_t)row * TVN);
    float4* s4 = (float4*)ys;
    s4[t] = g4[t];
    s4[t + 64] = g4[t + 64];
    __syncthreads();

    if (t == 0) {
        const float y0 = ys[0];
        int l = 256, r = 257;
        Knot L0, L1, R0, R1;
        L0.x = y0 - LAM; L0.a = 1.0f;  L0.b = LAM - y0;
        R0.x = y0 + LAM; R0.a = -1.0f; R0.b = LAM + y0;
        L1 = L0; R1 = R0;   // placeholders; size==2 -> slow paths (gated)
        kq[l] = make_float4(L0.x, L0.a, L0.b, 0.f);
        kq[r] = make_float4(R0.x, R0.a, R0.b, 0.f);
        ys[0] = L0.x;       // tm[0] overlay
        tpr[0] = R0.x;      // tp[0] spill
        float ycur = ys[1], ynext = ys[2];

#pragma unroll 1
        for (int i = 1; i <= TVN - 2; ++i) {
            float yfut = ys[(i + 2 <= TVN - 1) ? (i + 2) : (TVN - 1)];  // issued early
            const float bfirst = -LAM - ycur;
            const float blast  = -LAM + ycur;
            float tmv, tpv;

            // ================= LEFT scan (pop while fmaf(a,x,b) <= -lam) =================
            {
                const bool fast = (r - l >= 2);
                const float blo1 = bfirst + L0.b;
                const float alo1 = 1.0f + L0.a;
                const float d0 = L0.x + bfirst;            // fmaf(1, x, b)
                const float d1 = fmaf(alo1, L1.x, blo1);
                const bool p0 = !(d0 > -LAM);              // >=1 pop
                const bool deep = p0 && !(d1 > -LAM);      // >=2 pops
                if (fast && !deep) {
                    const float aN = p0 ? alo1 : 1.0f;
                    const float bN = p0 ? blo1 : bfirst;
                    const float tm0 = -LAM - bN;
                    tmv = p0 ? tm0 * __builtin_amdgcn_rcpf(aN) : tm0;
                    l -= p0 ? 0 : 1;
                    L1 = p0 ? L1 : L0;
                    L0.x = tmv; L0.a = aN; L0.b = bN + LAM;
                    kq[l & RMASK] = make_float4(L0.x, L0.a, L0.b, 0.f);
                } else {
                    float alo = 1.0f, blo = bfirst;
                    int lo = l;
                    while (lo <= r) {
                        float4 kn = kq[lo & RMASK];
                        if (fmaf(alo, kn.x, blo) > -LAM) break;
                        alo += kn.y; blo += kn.z;
                        ++lo;
                    }
                    tmv = (-LAM - blo) * __builtin_amdgcn_rcpf(alo);
                    l = lo - 1;
                    L0.x = tmv; L0.a = alo; L0.b = blo + LAM;
                    kq[l & RMASK] = make_float4(L0.x, L0.a, L0.b, 0.f);
                    if (l >= r) { r = l; R0 = L0; }        // ate whole deque
                    else { float4 kn = kq[(l + 1) & RMASK]; L1.x = kn.x; L1.a = kn.y; L1.b = kn.z; }
                }
            }
            if (l == r - 1) R1 = L0;   // fresh left knot sits just under R0

            // ============ RIGHT scan (pop while -(fmaf(a,x,b)) >= lam) — FIXED ============
            {
                const bool fast = (r - l >= 2);
                const float bhi1 = blast + R0.b;
                const float ahi1 = -1.0f + R0.a;
                const float e0 = R0.x - blast;             // -(fmaf(-1, x, blast))
                const float e1 = -fmaf(ahi1, R1.x, bhi1);
                const bool q0 = (e0 >= LAM);               // >=1 pop  [FIXED]
                const bool deep = q0 && (e1 >= LAM);       // >=2 pops [FIXED]
                if (fast && !deep) {
                    const float aN = q0 ? ahi1 : -1.0f;
                    const float bN = q0 ? bhi1 : blast;
                    const float tp0 = LAM + bN;
                    tpv = q0 ? tp0 * __builtin_amdgcn_rcpf(-aN) : tp0;
                    r += q0 ? 0 : 1;
                    R1 = q0 ? R1 : R0;
                    R0.x = tpv; R0.a = aN; R0.b = bN + LAM;
                    kq[r & RMASK] = make_float4(R0.x, R0.a, R0.b, 0.f);
                } else {
                    float ahi = -1.0f, bhi = blast;
                    int hi = r;
                    while (hi >= l) {
                        float4 kn = kq[hi & RMASK];
                        if (-fmaf(ahi, kn.x, bhi) < LAM) break;   // keep: derivative < lam [FIXED]
                        ahi += kn.y; bhi += kn.z;
                        --hi;
                    }
                    tpv = (LAM + bhi) * __builtin_amdgcn_rcpf(-ahi);
                    r = hi + 1;
                    R0.x = tpv; R0.a = ahi; R0.b = bhi + LAM;
                    kq[r & RMASK] = make_float4(R0.x, R0.a, R0.b, 0.f);
                    if (r <= l) { l = r; L0 = R0; }        // ate whole deque
                    else if (r - 1 == l) R1 = L0;
                    else { float4 kn = kq[(r - 1) & RMASK]; R1.x = kn.x; R1.a = kn.y; R1.b = kn.z; }
                }
            }
            if (r == l + 1) L1 = R0;

            ys[i] = tmv;       // tm overlay
            tpr[i] = tpv;      // tp spill (fire-and-forget global)
            ycur = ynext; ynext = yfut;
        }

        // ---- last coefficient: minimize (derivative == 0): pop while fmaf <= 0 ----
        float alo = 1.0f, blo = -LAM - ycur;   // ycur == y[N-1]
        {
            int lo = l;
            while (lo <= r) {
                float4 kn = kq[lo & RMASK];
                if (fmaf(alo, kn.x, blo) > 0.0f) break;
                alo += kn.y; blo += kn.z;
                ++lo;
            }
        }
        float b_prev = -blo * __builtin_amdgcn_rcpf(alo);

        // ---------- backward: beta[i] = clip(beta[i+1], tm[i], tp[i]) ----------
        // tm in ys (overlay), tp in global tpr. Betas overlay ys.
        float tp510 = tpr[510], tp509 = tpr[509], tp508 = tpr[508];   // prefetch head
        const float4* __restrict__ tp4 = (const float4*)tpr;
        float4* __restrict__ ym4 = (float4*)ys;
        float4 tpn = tp4[126];          // prefetch first group
        float4 tmn = ym4[126];
        ys[TVN - 1] = b_prev;
        b_prev = fminf(fmaxf(b_prev, ys[510]), tp510); ys[510] = b_prev;
        b_prev = fminf(fmaxf(b_prev, ys[509]), tp509); ys[509] = b_prev;
        b_prev = fminf(fmaxf(b_prev, ys[508]), tp508); ys[508] = b_prev;
#pragma unroll 4
        for (int g = 126; g >= 0; --g) {       // indices 507..0
            float4 tm_ = tmn, tp_ = tpn;
            if (g > 0) { tmn = ym4[g - 1]; tpn = tp4[g - 1]; }
            float4 bo;
            b_prev = fminf(fmaxf(b_prev, tm_.w), tp_.w); bo.w = b_prev;
            b_prev = fminf(fmaxf(b_prev, tm_.z), tp_.z); bo.z = b_prev;
            b_prev = fminf(fmaxf(b_prev, tm_.y), tp_.y); bo.y = b_prev;
            b_prev = fminf(fmaxf(b_prev, tm_.x), tp_.x); bo.x = b_prev;
            ym4[g] = bo;
        }
    }
    __syncthreads();

    // ---------- sparsemax via Michelot fixed point over betas in ys ----------
    float4 a = ((const float4*)ys)[t];
    float4 b = ((const float4*)ys)[t + 64];
    float v[8] = {a.x, a.y, a.z, a.w, b.x, b.y, b.z, b.w};

    float ls = v[0] + v[1] + v[2] + v[3] + v[4] + v[5] + v[6] + v[7];
    float S = wave_reduce_sum(ls);
    float tau = (S - 1.0f) * (1.0f / (float)TVN);
    int cprev = TVN;
#pragma unroll 1
    for (int it = 0; it < TVN; ++it) {
        float s = 0.0f, c = 0.0f;
#pragma unroll
        for (int j = 0; j < 8; ++j) {
            if (v[j] > tau) { s += v[j]; c += 1.0f; }
        }
        s = wave_reduce_sum(s);
        c = wave_reduce_sum(c);
        tau = (s - 1.0f) / c;
        int ci = (int)c;
        if (ci == cprev) break;
        cprev = ci;
    }

    float4 oa, ob;
    oa.x = fmaxf(v[0] - tau, 0.0f);
    oa.y = fmaxf(v[1] - tau, 0.0f);
    oa.z = fmaxf(v[2] - tau, 0.0f);
    oa.w = fmaxf(v[3] - tau, 0.0f);
    ob.x = fmaxf(v[4] - tau, 0.0f);
    ob.y = fmaxf(v[5] - tau, 0.0f);
    ob.z = fmaxf(v[6] - tau, 0.0f);
    ob.w = fmaxf(v[7] - tau, 0.0f);
    float4* __restrict__ o4 = (float4*)(out + (size_t)row * TVN);
    o4[t] = oa;
    o4[t + 64] = ob;
}

extern "C" void kernel_launch(void* const* d_in, const int* in_sizes, int n_in,
                              void* d_out, int out_size, void* d_ws, size_t ws_size,
                              hipStream_t stream) {
    const float* x = (const float*)d_in[0];
    float* out = (float*)d_out;
    const int rows = in_sizes[0] / TVN;   // 4096
    fusedmax_kernel<<<dim3(rows), dim3(64), 0, stream>>>(x, out);
}